// Round 10
// baseline (552.814 us; speedup 1.0000x reference)
//
#include <hip/hip_runtime.h>

// Shapes (fixed by the problem)
#define Bx 16
#define Cx 256
#define Dx 32
#define Nx 2304   // 48*48

typedef _Float16 f16;
typedef _Float16 f16x4 __attribute__((ext_vector_type(4)));
typedef _Float16 f16x8 __attribute__((ext_vector_type(8)));
typedef float    f32x4 __attribute__((ext_vector_type(4)));
typedef float    f32x16 __attribute__((ext_vector_type(16)));
typedef unsigned int u32x2 __attribute__((ext_vector_type(2)));
typedef unsigned int u32x4 __attribute__((ext_vector_type(4)));

// A,B fragment layouts (gfx950):
//  32x32x16_f16: lane holds A[m=lane%32][k=(lane/32)*8 + 0..7]  (f16x8)
//  C/D 32x32   : col=lane&31, row=(reg&3)+8*(reg>>2)+4*(lane>>5)  [verified]
#define MFMA_K16(a, b, c) __builtin_amdgcn_mfma_f32_32x32x16_f16((a), (b), (c), 0, 0, 0)
#define EXP2F(x) __builtin_amdgcn_exp2f(x)

// Repack two f16x4 B-frags of the K8 layout (j-granularity 4 per lane-half)
// into one f16x8 B-frag of the K16 layout (j-granularity 8 per lane-half).
// (R1/R2/R5/R7-verified correct.)
__device__ __forceinline__ f16x8 swap_pack(f16x4 a, f16x4 b) {
    u32x2 au = __builtin_bit_cast(u32x2, a);
    u32x2 bu = __builtin_bit_cast(u32x2, b);
    unsigned a0 = au[0], a1 = au[1], b0 = bu[0], b1 = bu[1];
    asm("v_permlane32_swap_b32 %0, %1" : "+v"(a0), "+v"(b0));
    asm("v_permlane32_swap_b32 %0, %1" : "+v"(a1), "+v"(b1));
    u32x4 r = {a0, a1, b0, b1};
    return __builtin_bit_cast(f16x8, r);
}

// ---------------------------------------------------------------------------
// Kernel A: q/k projections fused -> f16 hi/lo, layout [b][n][d].
// (R7-passing version, unchanged: 256 thr, 9 n-tiles.) q pre-scaled by 1/ln2.
// grid: Bx * 4 * 9 = 576 blocks, 256 threads.
// ---------------------------------------------------------------------------
__global__ __launch_bounds__(256) void qk_proj(
    const float* __restrict__ x,
    const float* __restrict__ Wq, const float* __restrict__ bq,
    const float* __restrict__ Wk, const float* __restrict__ bk,
    f16* __restrict__ qhi, f16* __restrict__ qlo,
    f16* __restrict__ khi, f16* __restrict__ klo) {
    int bid = blockIdx.x;
    int nt = bid % 9;  bid /= 9;
    int dc = bid % 4;  bid /= 4;
    int b  = bid;                     // 0..15

    int n  = nt * 256 + threadIdx.x;
    int d0 = dc * 8;
    float aq[8], ak[8];
#pragma unroll
    for (int dd = 0; dd < 8; ++dd) { aq[dd] = bq[d0 + dd]; ak[dd] = bk[d0 + dd]; }

    const float* xcol = x + (size_t)b * Cx * Nx + n;
    const float* wq0  = Wq + (size_t)d0 * Cx;
    const float* wk0  = Wk + (size_t)d0 * Cx;
    for (int c = 0; c < Cx; ++c) {
        float xv = xcol[(size_t)c * Nx];
#pragma unroll
        for (int dd = 0; dd < 8; ++dd) {
            aq[dd] += wq0[dd * Cx + c] * xv;
            ak[dd] += wk0[dd * Cx + c] * xv;
        }
    }
    const float SC = 1.4426950408889634f;  // 1/ln2 on q
    f16x8 qh, ql, kh, kl;
#pragma unroll
    for (int dd = 0; dd < 8; ++dd) {
        float a = aq[dd] * SC;
        f16 h = (f16)a;
        qh[dd] = h; ql[dd] = (f16)(a - (float)h);
        float kk = ak[dd];
        f16 hk = (f16)kk;
        kh[dd] = hk; kl[dd] = (f16)(kk - (float)hk);
    }
    size_t base = ((size_t)b * Nx + n) * Dx + d0;
    *(f16x8*)(qhi + base) = qh;
    *(f16x8*)(qlo + base) = ql;
    *(f16x8*)(khi + base) = kh;
    *(f16x8*)(klo + base) = kl;
}

// ---------------------------------------------------------------------------
// Kernel B: v projection -> f16 hi/lo, layout [b][c][n]. (passing, unchanged)
// ---------------------------------------------------------------------------
__global__ __launch_bounds__(256) void v_proj(
    const float* __restrict__ x,
    const float* __restrict__ Wv, const float* __restrict__ bv,
    f16* __restrict__ vhi, f16* __restrict__ vlo) {
    __shared__ float sx[Cx * 16];
    int bid = blockIdx.x;
    int nt = bid % (Nx / 16);
    int b  = bid / (Nx / 16);
    int n0 = nt * 16;
    int t  = threadIdx.x;

    for (int r = 0; r < 16; ++r) {
        int f = r * 256 + t;
        int c = f >> 4, nn = f & 15;
        sx[f] = x[((size_t)b * Cx + c) * Nx + n0 + nn];
    }
    __syncthreads();

    float acc[16];
    float bvv = bv[t];
#pragma unroll
    for (int nn = 0; nn < 16; ++nn) acc[nn] = bvv;

    const float* wrow = Wv + (size_t)t * Cx;
    for (int c = 0; c < Cx; ++c) {
        float wv = wrow[c];
        const float4* sxr = (const float4*)&sx[c * 16];
#pragma unroll
        for (int g = 0; g < 4; ++g) {
            float4 xv = sxr[g];
            acc[g * 4 + 0] += wv * xv.x;
            acc[g * 4 + 1] += wv * xv.y;
            acc[g * 4 + 2] += wv * xv.z;
            acc[g * 4 + 3] += wv * xv.w;
        }
    }
    f16x8 h0, l0, h1, l1;
#pragma unroll
    for (int nn = 0; nn < 8; ++nn) {
        f16 h = (f16)acc[nn];
        h0[nn] = h; l0[nn] = (f16)(acc[nn] - (float)h);
    }
#pragma unroll
    for (int nn = 0; nn < 8; ++nn) {
        f16 h = (f16)acc[8 + nn];
        h1[nn] = h; l1[nn] = (f16)(acc[8 + nn] - (float)h);
    }
    size_t base = ((size_t)b * Cx + t) * Nx + n0;
    *(f16x8*)(vhi + base)     = h0;
    *(f16x8*)(vhi + base + 8) = h1;
    *(f16x8*)(vlo + base)     = l0;
    *(f16x8*)(vlo + base + 8) = l1;
}

// ---------------------------------------------------------------------------
// Kernel C: softmax column sums  s[b][j] = sum_i exp2(E[i,j]).
// 4 waves per block, LDS partial reduce. (passing, unchanged)
// ---------------------------------------------------------------------------
__global__ __launch_bounds__(256, 4) void col_stats(
    const f16* __restrict__ qhi, const f16* __restrict__ qlo,
    const f16* __restrict__ khi, const f16* __restrict__ klo,
    float* __restrict__ s) {
    __shared__ float part[4][32];
    int jt = blockIdx.x % 72;
    int b  = blockIdx.x / 72;
    int j0 = jt * 32;
    int t  = threadIdx.x;
    int w  = t >> 6;              // wave id 0..3
    int il = t & 31, h = (t >> 5) & 1;

    f16x8 kh[2], kl[2];
#pragma unroll
    for (int ks = 0; ks < 2; ++ks) {
        size_t off = ((size_t)b * Nx + j0 + il) * Dx + h * 8 + ks * 16;
        kh[ks] = *(const f16x8*)(khi + off);
        kl[ks] = *(const f16x8*)(klo + off);
    }
    f32x16 sacc = {};
    for (int it = w * 18; it < w * 18 + 18; ++it) {
        f16x8 qh[2], ql[2];
#pragma unroll
        for (int ks = 0; ks < 2; ++ks) {
            size_t off = ((size_t)b * Nx + it * 32 + il) * Dx + h * 8 + ks * 16;
            qh[ks] = *(const f16x8*)(qhi + off);
            ql[ks] = *(const f16x8*)(qlo + off);
        }
        f32x16 e = {};
        __builtin_amdgcn_s_setprio(1);
        e = MFMA_K16(kh[0], qh[0], e);
        e = MFMA_K16(kh[0], ql[0], e);
        e = MFMA_K16(kl[0], qh[0], e);
        e = MFMA_K16(kh[1], qh[1], e);
        e = MFMA_K16(kh[1], ql[1], e);
        e = MFMA_K16(kl[1], qh[1], e);
        __builtin_amdgcn_s_setprio(0);
#pragma unroll
        for (int r = 0; r < 16; ++r) sacc[r] += EXP2F(e[r]);
    }
#pragma unroll
    for (int r = 0; r < 16; ++r) {
        float v = sacc[r];
        for (int msk = 1; msk <= 16; msk <<= 1) v += __shfl_xor(v, msk);
        if (il == 0) part[w][(r & 3) + 8 * (r >> 2) + 4 * h] = v;
    }
    __syncthreads();
    if (t < 32)
        s[(size_t)b * Nx + j0 + t] =
            part[0][t] + part[1][t] + part[2][t] + part[3][t];
}

// ---------------------------------------------------------------------------
// Kernel D: main.  R10 = R7 byte-identical EXCEPT the epilogue exchange
// buffer: red[2][64][33] (16.9 KB) -> SEPARATE red[64][33] (8.4 KB), used
// twice (chunked per itile, barrier-separated). No union, no reinterpret,
// launch_bounds unchanged (128,2). LDS 26112 -> 17664 B:
//   LDS cap 9 blocks/CU; VGPR cap (124) 8 blocks/CU -> 16 waves/CU resident
//   vs R7's LDS-capped 6. Pure occupancy change; j-loop untouched.
// grid: Bx * 36 * 4 = 2304 blocks, 128 threads.
// ---------------------------------------------------------------------------
__global__ __launch_bounds__(128, 2) void attn_out(
    const f16* __restrict__ qhi, const f16* __restrict__ qlo,
    const f16* __restrict__ khi, const f16* __restrict__ klo,
    const f16* __restrict__ vhi, const f16* __restrict__ vlo,
    const float* __restrict__ s, const float* __restrict__ x,
    const float* __restrict__ gamma, float* __restrict__ out) {
    __shared__ __align__(16) float rs[Nx];     // 9216 B
    __shared__ float red[64][33];              // 8448 B, padded, chunk-reused
    int blk = blockIdx.x;
    int w4   = blk & 3;  blk >>= 2;     // c-quarter
    int it64 = blk % 36;
    int b    = blk / 36;
    int i0   = it64 * 64;
    int c0   = w4 * 64;
    int t = threadIdx.x;
    int jh   = t >> 6;                  // wave id = j-half (0..1)
    int lane = t & 63;
    int il = t & 31, h = (t >> 5) & 1;

    {   // stage reciprocal sums (128 threads)
        const f32x4* s4 = (const f32x4*)(s + (size_t)b * Nx);
        f32x4* rs4 = (f32x4*)rs;
        for (int r = t; r < Nx / 4; r += 128) {
            f32x4 v = s4[r];
            rs4[r] = (f32x4){1.0f / v[0], 1.0f / v[1], 1.0f / v[2], 1.0f / v[3]};
        }
    }
    __syncthreads();

    // Q as B-operand for E^T, both i-subtiles, hoisted
    f16x8 qh[2][2], ql[2][2];   // [itile][ks]
#pragma unroll
    for (int itile = 0; itile < 2; ++itile)
#pragma unroll
        for (int ks = 0; ks < 2; ++ks) {
            size_t off = ((size_t)b * Nx + i0 + itile * 32 + il) * Dx + h * 8 + ks * 16;
            qh[itile][ks] = *(const f16x8*)(qhi + off);
            ql[itile][ks] = *(const f16x8*)(qlo + off);
        }

    f32x16 acc[2][2];  // [itile][cg]
#pragma unroll
    for (int a = 0; a < 2; ++a)
#pragma unroll
        for (int cgi = 0; cgi < 2; ++cgi) acc[a][cgi] = (f32x16){};

    int jb = jh * 36 * 32;
    const f16* kph = khi + ((size_t)b * Nx + jb + il) * Dx + h * 8;
    const f16* kpl = klo + ((size_t)b * Nx + jb + il) * Dx + h * 8;
    const f16* vph = vhi + ((size_t)b * Cx + c0 + il) * Nx + jb + h * 8;
    const f16* vpl = vlo + ((size_t)b * Cx + c0 + il) * Nx + jb + h * 8;

    // K double-buffer (K(j) lives in buf j&1), V single-buffer
    f16x8 kh[2][2], kl[2][2];    // [buf][ks]
    f16x8 vh8[2][2], vl8[2][2];  // [cg][gp]

    // prologue: K0 -> buf0, K1 -> buf1, V0
#pragma unroll
    for (int ks = 0; ks < 2; ++ks) {
        kh[0][ks] = *(const f16x8*)(kph + ks * 16);
        kl[0][ks] = *(const f16x8*)(kpl + ks * 16);
        kh[1][ks] = *(const f16x8*)(kph + 1024 + ks * 16);
        kl[1][ks] = *(const f16x8*)(kpl + 1024 + ks * 16);
    }
#pragma unroll
    for (int cg = 0; cg < 2; ++cg)
#pragma unroll
        for (int gp = 0; gp < 2; ++gp) {
            size_t voff = (size_t)cg * 32 * Nx + gp * 16;
            vh8[cg][gp] = *(const f16x8*)(vph + voff);
            vl8[cg][gp] = *(const f16x8*)(vpl + voff);
        }

    // prologue: E(0) for both itiles into pe[]
    f32x16 pe[2];
#pragma unroll
    for (int itile = 0; itile < 2; ++itile) {
        f32x16 e = {};
        e = MFMA_K16(kh[0][0], qh[itile][0], e);
        e = MFMA_K16(kh[0][0], ql[itile][0], e);
        e = MFMA_K16(kl[0][0], qh[itile][0], e);
        e = MFMA_K16(kh[0][1], qh[itile][1], e);
        e = MFMA_K16(kh[0][1], ql[itile][1], e);
        e = MFMA_K16(kl[0][1], qh[itile][1], e);
        pe[itile] = e;
    }

#pragma unroll 2
    for (int jt = 0; jt < 36; ++jt) {
        int cur = jt & 1, nxt = cur ^ 1;     // K(jt+1) = buf nxt
        int j0  = jb + jt * 32;
        // ---- issue K(jt+2) into buf cur (K(jt) fully consumed last iter) ----
        int kn = (jt + 2 < 36) ? (jt + 2) * 1024 : 0;
#pragma unroll
        for (int ks = 0; ks < 2; ++ks) {
            kh[cur][ks] = *(const f16x8*)(kph + kn + ks * 16);
            kl[cur][ks] = *(const f16x8*)(kpl + kn + ks * 16);
        }
#pragma unroll
        for (int itile = 0; itile < 2; ++itile) {
            // ---- pack P(jt) from pe[itile]: exp2 * rs, f16 hi/lo, K16 frags ----
            f16x4 ph4[4], pl4[4];
#pragma unroll
            for (int g = 0; g < 4; ++g) {
                f32x4 rsv = *(const f32x4*)&rs[j0 + 8 * g + 4 * h];
#pragma unroll
                for (int jj = 0; jj < 4; ++jj) {
                    float p = EXP2F(pe[itile][4 * g + jj]) * rsv[jj];
                    f16 hh = (f16)p;
                    ph4[g][jj] = hh;
                    pl4[g][jj] = (f16)(p - (float)hh);
                }
            }
            f16x8 phK[2], plK[2];
#pragma unroll
            for (int gp = 0; gp < 2; ++gp) {
                phK[gp] = swap_pack(ph4[2 * gp], ph4[2 * gp + 1]);
                plK[gp] = swap_pack(pl4[2 * gp], pl4[2 * gp + 1]);
            }
            __builtin_amdgcn_s_setprio(1);
            // ---- E(jt+1): independent MFMA chain, overlaps PV below ----
            {
                f32x16 e = {};
                e = MFMA_K16(kh[nxt][0], qh[itile][0], e);
                e = MFMA_K16(kh[nxt][0], ql[itile][0], e);
                e = MFMA_K16(kl[nxt][0], qh[itile][0], e);
                e = MFMA_K16(kh[nxt][1], qh[itile][1], e);
                e = MFMA_K16(kh[nxt][1], ql[itile][1], e);
                e = MFMA_K16(kl[nxt][1], qh[itile][1], e);
                pe[itile] = e;   // jt=35 writes junk (K wrapped); never packed
            }
            // ---- PV(jt): acc += V * P^T ----
#pragma unroll
            for (int cg = 0; cg < 2; ++cg)
#pragma unroll
                for (int gp = 0; gp < 2; ++gp) {
                    acc[itile][cg] = MFMA_K16(vh8[cg][gp], phK[gp], acc[itile][cg]);
                    acc[itile][cg] = MFMA_K16(vh8[cg][gp], plK[gp], acc[itile][cg]);
                    acc[itile][cg] = MFMA_K16(vl8[cg][gp], phK[gp], acc[itile][cg]);
                }
            __builtin_amdgcn_s_setprio(0);
        }
        // ---- late-issue V(jt+1); consumed after next iter's pack+E ----
        int vn = (jt + 1 < 36) ? (jt + 1) * 32 : 0;
#pragma unroll
        for (int cg = 0; cg < 2; ++cg)
#pragma unroll
            for (int gp = 0; gp < 2; ++gp) {
                size_t voff = (size_t)cg * 32 * Nx + vn + gp * 16;
                vh8[cg][gp] = *(const f16x8*)(vph + voff);
                vl8[cg][gp] = *(const f16x8*)(vpl + voff);
            }
    }

    // ---- combine j-halves via the chunked red buffer (one itile at a time)
    float gm = gamma[0];
#pragma unroll
    for (int itile = 0; itile < 2; ++itile) {
        __syncthreads();   // itile0: j-loop rs reads done; itile1: prev reads done
        if (jh == 1) {
#pragma unroll
            for (int cg = 0; cg < 2; ++cg)
#pragma unroll
                for (int r = 0; r < 16; ++r)
                    red[lane][cg * 16 + r] = acc[itile][cg][r];
        }
        __syncthreads();
        if (jh == 0) {
#pragma unroll
            for (int cg = 0; cg < 2; ++cg)
#pragma unroll
                for (int r = 0; r < 16; ++r) {
                    int c = c0 + cg * 32 + (r & 3) + 8 * (r >> 2) + 4 * h;
                    int i = i0 + itile * 32 + il;
                    size_t idx = ((size_t)b * Cx + c) * Nx + i;
                    out[idx] = x[idx] +
                        gm * (acc[itile][cg][r] + red[lane][cg * 16 + r]);
                }
        }
    }
}

// ---------------------------------------------------------------------------
extern "C" void kernel_launch(void* const* d_in, const int* in_sizes, int n_in,
                              void* d_out, int out_size, void* d_ws, size_t ws_size,
                              hipStream_t stream) {
    const float* x     = (const float*)d_in[0];
    const float* Wq    = (const float*)d_in[1];
    const float* bq    = (const float*)d_in[2];
    const float* Wk    = (const float*)d_in[3];
    const float* bk    = (const float*)d_in[4];
    const float* Wv    = (const float*)d_in[5];
    const float* bv    = (const float*)d_in[6];
    const float* gamma = (const float*)d_in[7];
    float* out = (float*)d_out;

    const size_t QK = (size_t)Bx * Nx * Dx;
    const size_t VN = (size_t)Bx * Cx * Nx;
    f16* qhi = (f16*)d_ws;
    f16* qlo = qhi + QK;
    f16* khi = qlo + QK;
    f16* klo = khi + QK;
    f16* vhi = klo + QK;
    f16* vlo = vhi + VN;
    float* s = (float*)(vlo + VN);

    qk_proj  <<<Bx * 4 * 9,     256, 0, stream>>>(x, Wq, bq, Wk, bk, qhi, qlo, khi, klo);
    v_proj   <<<Bx * (Nx / 16), 256, 0, stream>>>(x, Wv, bv, vhi, vlo);
    col_stats<<<Bx * 72,        256, 0, stream>>>(qhi, qlo, khi, klo, s);
    attn_out <<<Bx * 36 * 4,    128, 0, stream>>>(qhi, qlo, khi, klo, vhi, vlo, s, x, gamma, out);
}

// Round 11
// 402.731 us; speedup vs baseline: 1.3727x; 1.3727x over previous
//
#include <hip/hip_runtime.h>

// Shapes (fixed by the problem)
#define Bx 16
#define Cx 256
#define Dx 32
#define Nx 2304   // 48*48

typedef _Float16 f16;
typedef _Float16 f16x4 __attribute__((ext_vector_type(4)));
typedef _Float16 f16x8 __attribute__((ext_vector_type(8)));
typedef float    f32x4 __attribute__((ext_vector_type(4)));
typedef float    f32x16 __attribute__((ext_vector_type(16)));
typedef unsigned int u32x2 __attribute__((ext_vector_type(2)));
typedef unsigned int u32x4 __attribute__((ext_vector_type(4)));

// A,B fragment layouts (gfx950):
//  32x32x16_f16: lane holds A[m=lane%32][k=(lane/32)*8 + 0..7]  (f16x8)
//  C/D 32x32   : col=lane&31, row=(reg&3)+8*(reg>>2)+4*(lane>>5)  [verified]
#define MFMA_K16(a, b, c) __builtin_amdgcn_mfma_f32_32x32x16_f16((a), (b), (c), 0, 0, 0)
#define EXP2F(x) __builtin_amdgcn_exp2f(x)

// Repack two f16x4 B-frags of the K8 layout (j-granularity 4 per lane-half)
// into one f16x8 B-frag of the K16 layout (j-granularity 8 per lane-half).
// (R1/R2/R5/R7/R10-verified correct.)
__device__ __forceinline__ f16x8 swap_pack(f16x4 a, f16x4 b) {
    u32x2 au = __builtin_bit_cast(u32x2, a);
    u32x2 bu = __builtin_bit_cast(u32x2, b);
    unsigned a0 = au[0], a1 = au[1], b0 = bu[0], b1 = bu[1];
    asm("v_permlane32_swap_b32 %0, %1" : "+v"(a0), "+v"(b0));
    asm("v_permlane32_swap_b32 %0, %1" : "+v"(a1), "+v"(b1));
    u32x4 r = {a0, a1, b0, b1};
    return __builtin_bit_cast(f16x8, r);
}

// ---------------------------------------------------------------------------
// Kernel A: fused q/k projection -> SINGLE f16 per element (R11: lo-planes
// dropped; error budget analysis in journal). q pre-scaled by 1/ln2.
// grid: Bx * 4 * 9 = 576 blocks, 256 threads.
// ---------------------------------------------------------------------------
__global__ __launch_bounds__(256) void qk_proj(
    const float* __restrict__ x,
    const float* __restrict__ Wq, const float* __restrict__ bq,
    const float* __restrict__ Wk, const float* __restrict__ bk,
    f16* __restrict__ qhi, f16* __restrict__ khi) {
    int bid = blockIdx.x;
    int nt = bid % 9;  bid /= 9;
    int dc = bid % 4;  bid /= 4;
    int b  = bid;                     // 0..15

    int n  = nt * 256 + threadIdx.x;
    int d0 = dc * 8;
    float aq[8], ak[8];
#pragma unroll
    for (int dd = 0; dd < 8; ++dd) { aq[dd] = bq[d0 + dd]; ak[dd] = bk[d0 + dd]; }

    const float* xcol = x + (size_t)b * Cx * Nx + n;
    const float* wq0  = Wq + (size_t)d0 * Cx;
    const float* wk0  = Wk + (size_t)d0 * Cx;
    for (int c = 0; c < Cx; ++c) {
        float xv = xcol[(size_t)c * Nx];
#pragma unroll
        for (int dd = 0; dd < 8; ++dd) {
            aq[dd] += wq0[dd * Cx + c] * xv;
            ak[dd] += wk0[dd * Cx + c] * xv;
        }
    }
    const float SC = 1.4426950408889634f;  // 1/ln2 on q
    f16x8 qv, kv;
#pragma unroll
    for (int dd = 0; dd < 8; ++dd) {
        qv[dd] = (f16)(aq[dd] * SC);
        kv[dd] = (f16)ak[dd];
    }
    size_t base = ((size_t)b * Nx + n) * Dx + d0;
    *(f16x8*)(qhi + base) = qv;
    *(f16x8*)(khi + base) = kv;
}

// ---------------------------------------------------------------------------
// Kernel B: v projection -> SINGLE f16, layout [b][c][n]. (R11: vlo dropped)
// ---------------------------------------------------------------------------
__global__ __launch_bounds__(256) void v_proj(
    const float* __restrict__ x,
    const float* __restrict__ Wv, const float* __restrict__ bv,
    f16* __restrict__ vhi) {
    __shared__ float sx[Cx * 16];
    int bid = blockIdx.x;
    int nt = bid % (Nx / 16);
    int b  = bid / (Nx / 16);
    int n0 = nt * 16;
    int t  = threadIdx.x;

    for (int r = 0; r < 16; ++r) {
        int f = r * 256 + t;
        int c = f >> 4, nn = f & 15;
        sx[f] = x[((size_t)b * Cx + c) * Nx + n0 + nn];
    }
    __syncthreads();

    float acc[16];
    float bvv = bv[t];
#pragma unroll
    for (int nn = 0; nn < 16; ++nn) acc[nn] = bvv;

    const float* wrow = Wv + (size_t)t * Cx;
    for (int c = 0; c < Cx; ++c) {
        float wv = wrow[c];
        const float4* sxr = (const float4*)&sx[c * 16];
#pragma unroll
        for (int g = 0; g < 4; ++g) {
            float4 xv = sxr[g];
            acc[g * 4 + 0] += wv * xv.x;
            acc[g * 4 + 1] += wv * xv.y;
            acc[g * 4 + 2] += wv * xv.z;
            acc[g * 4 + 3] += wv * xv.w;
        }
    }
    f16x8 h0, h1;
#pragma unroll
    for (int nn = 0; nn < 8; ++nn) {
        h0[nn] = (f16)acc[nn];
        h1[nn] = (f16)acc[8 + nn];
    }
    size_t base = ((size_t)b * Cx + t) * Nx + n0;
    *(f16x8*)(vhi + base)     = h0;
    *(f16x8*)(vhi + base + 8) = h1;
}

// ---------------------------------------------------------------------------
// Kernel C: softmax column sums  s[b][j] = sum_i exp2(E[i,j]).
// R11: single-f16 q,k -> 2 MFMA per i-tile, half the loads. Uses the SAME
// rounded operands as attn_out, so the normalization stays consistent.
// grid: Bx * 72 blocks, 256 threads.
// ---------------------------------------------------------------------------
__global__ __launch_bounds__(256, 4) void col_stats(
    const f16* __restrict__ qhi, const f16* __restrict__ khi,
    float* __restrict__ s) {
    __shared__ float part[4][32];
    int jt = blockIdx.x % 72;
    int b  = blockIdx.x / 72;
    int j0 = jt * 32;
    int t  = threadIdx.x;
    int w  = t >> 6;              // wave id 0..3
    int il = t & 31, h = (t >> 5) & 1;

    f16x8 kh[2];
#pragma unroll
    for (int ks = 0; ks < 2; ++ks)
        kh[ks] = *(const f16x8*)(khi + ((size_t)b * Nx + j0 + il) * Dx + h * 8 + ks * 16);

    f32x16 sacc = {};
    for (int it = w * 18; it < w * 18 + 18; ++it) {
        f16x8 qh[2];
#pragma unroll
        for (int ks = 0; ks < 2; ++ks)
            qh[ks] = *(const f16x8*)(qhi + ((size_t)b * Nx + it * 32 + il) * Dx + h * 8 + ks * 16);
        f32x16 e = {};
        __builtin_amdgcn_s_setprio(1);
        e = MFMA_K16(kh[0], qh[0], e);
        e = MFMA_K16(kh[1], qh[1], e);
        __builtin_amdgcn_s_setprio(0);
#pragma unroll
        for (int r = 0; r < 16; ++r) sacc[r] += EXP2F(e[r]);
    }
#pragma unroll
    for (int r = 0; r < 16; ++r) {
        float v = sacc[r];
        for (int msk = 1; msk <= 16; msk <<= 1) v += __shfl_xor(v, msk);
        if (il == 0) part[w][(r & 3) + 8 * (r >> 2) + 4 * h] = v;
    }
    __syncthreads();
    if (t < 32)
        s[(size_t)b * Nx + j0 + t] =
            part[0][t] + part[1][t] + part[2][t] + part[3][t];
}

// ---------------------------------------------------------------------------
// Kernel D: main.  R11: single-f16 operands everywhere (q,k,V,P).
//  - MFMA/iter 36 -> 12 (E: 2/itile, PV: 4/itile); pack VALU halved.
//  - loads/iter 12 -> 6 dwordx4; BOTH K and V double-buffered at
//    prefetch distance 2 (~1+ iter of cover for L3/HBM latency).
//  - register footprint ~160 incl. accumulators -> 3 waves/SIMD under
//    __launch_bounds__(128,3) (the R10 lesson: acc AGPRs count against the
//    unified file; VGPR_Count=124 hid a ~250-reg true footprint).
// grid: Bx * 36 * 4 = 2304 blocks, 128 threads (2 waves = j-halves).
// ---------------------------------------------------------------------------
__global__ __launch_bounds__(128, 3) void attn_out(
    const f16* __restrict__ qhi, const f16* __restrict__ khi,
    const f16* __restrict__ vhi,
    const float* __restrict__ s, const float* __restrict__ x,
    const float* __restrict__ gamma, float* __restrict__ out) {
    __shared__ __align__(16) float rs[Nx];     // 9216 B
    __shared__ float red[64][33];              // 8448 B, padded, chunk-reused
    int blk = blockIdx.x;
    int w4   = blk & 3;  blk >>= 2;     // c-quarter
    int it64 = blk % 36;
    int b    = blk / 36;
    int i0   = it64 * 64;
    int c0   = w4 * 64;
    int t = threadIdx.x;
    int jh   = t >> 6;                  // wave id = j-half (0..1)
    int lane = t & 63;
    int il = t & 31, h = (t >> 5) & 1;

    {   // stage reciprocal sums (128 threads)
        const f32x4* s4 = (const f32x4*)(s + (size_t)b * Nx);
        f32x4* rs4 = (f32x4*)rs;
        for (int r = t; r < Nx / 4; r += 128) {
            f32x4 v = s4[r];
            rs4[r] = (f32x4){1.0f / v[0], 1.0f / v[1], 1.0f / v[2], 1.0f / v[3]};
        }
    }
    __syncthreads();

    // Q as B-operand for E^T, both i-subtiles, hoisted (single f16)
    f16x8 qh[2][2];   // [itile][ks]
#pragma unroll
    for (int itile = 0; itile < 2; ++itile)
#pragma unroll
        for (int ks = 0; ks < 2; ++ks)
            qh[itile][ks] = *(const f16x8*)(qhi +
                ((size_t)b * Nx + i0 + itile * 32 + il) * Dx + h * 8 + ks * 16);

    f32x16 acc[2][2];  // [itile][cg]
#pragma unroll
    for (int a = 0; a < 2; ++a)
#pragma unroll
        for (int cgi = 0; cgi < 2; ++cgi) acc[a][cgi] = (f32x16){};

    int jb = jh * 36 * 32;
    const f16* kph = khi + ((size_t)b * Nx + jb + il) * Dx + h * 8;
    const f16* vph = vhi + ((size_t)b * Cx + c0 + il) * Nx + jb + h * 8;

    // K and V register double-buffers, both at prefetch distance 2
    f16x8 kb[2][2];     // [buf][ks]
    f16x8 vb[2][2][2];  // [buf][cg][gp]

    // prologue: tiles 0 and 1
#pragma unroll
    for (int ks = 0; ks < 2; ++ks) {
        kb[0][ks] = *(const f16x8*)(kph + ks * 16);
        kb[1][ks] = *(const f16x8*)(kph + 1024 + ks * 16);
    }
#pragma unroll
    for (int cg = 0; cg < 2; ++cg)
#pragma unroll
        for (int gp = 0; gp < 2; ++gp) {
            size_t voff = (size_t)cg * 32 * Nx + gp * 16;
            vb[0][cg][gp] = *(const f16x8*)(vph + voff);
            vb[1][cg][gp] = *(const f16x8*)(vph + voff + 32);
        }

#pragma unroll 2
    for (int jt = 0; jt < 36; ++jt) {
        int cur = jt & 1;
        int j0  = jb + jt * 32;
#pragma unroll
        for (int itile = 0; itile < 2; ++itile) {
            // ---- E^T tile (2 MFMA) ----
            f32x16 e = {};
            __builtin_amdgcn_s_setprio(1);
            e = MFMA_K16(kb[cur][0], qh[itile][0], e);
            e = MFMA_K16(kb[cur][1], qh[itile][1], e);
            __builtin_amdgcn_s_setprio(0);
            // ---- P^T = exp2(E^T)*rs[j], single f16; reg 4g+jj = j0+jj+8g+4h
            f16x4 ph4[4];
#pragma unroll
            for (int g = 0; g < 4; ++g) {
                f32x4 rsv = *(const f32x4*)&rs[j0 + 8 * g + 4 * h];
#pragma unroll
                for (int jj = 0; jj < 4; ++jj)
                    ph4[g][jj] = (f16)(EXP2F(e[4 * g + jj]) * rsv[jj]);
            }
            f16x8 phK[2];
            phK[0] = swap_pack(ph4[0], ph4[1]);
            phK[1] = swap_pack(ph4[2], ph4[3]);
            // ---- PV (4 MFMA) ----
            __builtin_amdgcn_s_setprio(1);
#pragma unroll
            for (int cg = 0; cg < 2; ++cg)
#pragma unroll
                for (int gp = 0; gp < 2; ++gp)
                    acc[itile][cg] = MFMA_K16(vb[cur][cg][gp], phK[gp], acc[itile][cg]);
            __builtin_amdgcn_s_setprio(0);
        }
        // ---- issue K(jt+2), V(jt+2) into buf cur (fully consumed above) ----
        int kn = (jt + 2 < 36) ? (jt + 2) * 1024 : 0;
#pragma unroll
        for (int ks = 0; ks < 2; ++ks)
            kb[cur][ks] = *(const f16x8*)(kph + kn + ks * 16);
        int vn = (jt + 2 < 36) ? (jt + 2) * 32 : 0;
#pragma unroll
        for (int cg = 0; cg < 2; ++cg)
#pragma unroll
            for (int gp = 0; gp < 2; ++gp) {
                size_t voff = (size_t)cg * 32 * Nx + vn + gp * 16;
                vb[cur][cg][gp] = *(const f16x8*)(vph + voff);
            }
    }

    // ---- combine j-halves via the chunked red buffer (R10-verified) ----
    float gm = gamma[0];
#pragma unroll
    for (int itile = 0; itile < 2; ++itile) {
        __syncthreads();
        if (jh == 1) {
#pragma unroll
            for (int cg = 0; cg < 2; ++cg)
#pragma unroll
                for (int r = 0; r < 16; ++r)
                    red[lane][cg * 16 + r] = acc[itile][cg][r];
        }
        __syncthreads();
        if (jh == 0) {
#pragma unroll
            for (int cg = 0; cg < 2; ++cg)
#pragma unroll
                for (int r = 0; r < 16; ++r) {
                    int c = c0 + cg * 32 + (r & 3) + 8 * (r >> 2) + 4 * h;
                    int i = i0 + itile * 32 + il;
                    size_t idx = ((size_t)b * Cx + c) * Nx + i;
                    out[idx] = x[idx] +
                        gm * (acc[itile][cg][r] + red[lane][cg * 16 + r]);
                }
        }
    }
}

// ---------------------------------------------------------------------------
extern "C" void kernel_launch(void* const* d_in, const int* in_sizes, int n_in,
                              void* d_out, int out_size, void* d_ws, size_t ws_size,
                              hipStream_t stream) {
    const float* x     = (const float*)d_in[0];
    const float* Wq    = (const float*)d_in[1];
    const float* bq    = (const float*)d_in[2];
    const float* Wk    = (const float*)d_in[3];
    const float* bk    = (const float*)d_in[4];
    const float* Wv    = (const float*)d_in[5];
    const float* bv    = (const float*)d_in[6];
    const float* gamma = (const float*)d_in[7];
    float* out = (float*)d_out;

    // ws layout: q, k: [b][n][d] f16; v: [b][c][n] f16; s: [b][n] f32
    const size_t QK = (size_t)Bx * Nx * Dx;
    const size_t VN = (size_t)Bx * Cx * Nx;
    f16* qhi = (f16*)d_ws;
    f16* khi = qhi + QK;
    f16* vhi = khi + QK;
    float* s = (float*)(vhi + VN);

    qk_proj  <<<Bx * 4 * 9,     256, 0, stream>>>(x, Wq, bq, Wk, bk, qhi, khi);
    v_proj   <<<Bx * (Nx / 16), 256, 0, stream>>>(x, Wv, bv, vhi);
    col_stats<<<Bx * 72,        256, 0, stream>>>(qhi, khi, s);
    attn_out <<<Bx * 36 * 4,    128, 0, stream>>>(qhi, khi, vhi, s, x, gamma, out);
}

// Round 12
// 278.888 us; speedup vs baseline: 1.9822x; 1.4441x over previous
//
#include <hip/hip_runtime.h>

// Shapes (fixed by the problem)
#define Bx 16
#define Cx 256
#define Dx 32
#define Nx 2304   // 48*48

typedef _Float16 f16;
typedef _Float16 f16x4 __attribute__((ext_vector_type(4)));
typedef _Float16 f16x8 __attribute__((ext_vector_type(8)));
typedef float    f32x4 __attribute__((ext_vector_type(4)));
typedef float    f32x16 __attribute__((ext_vector_type(16)));
typedef unsigned int u32x2 __attribute__((ext_vector_type(2)));
typedef unsigned int u32x4 __attribute__((ext_vector_type(4)));

// A,B fragment layouts (gfx950):
//  A: lane holds A[m=lane%32][k=(lane/32)*8 + 0..7]  (f16x8)
//  B: lane holds B[k=(lane/32)*8 + 0..7][n=lane%32]  — SAME per-lane memory
//     pattern as A (verified by col_stats: K-as-A / Q-as-B share addressing).
//  C/D: col=lane&31, row=(reg&3)+8*(reg>>2)+4*(lane>>5)  [verified]
#define MFMA_K16(a, b, c) __builtin_amdgcn_mfma_f32_32x32x16_f16((a), (b), (c), 0, 0, 0)
#define EXP2F(x) __builtin_amdgcn_exp2f(x)

// Repack two f16x4 B-frags of the K8 layout into one f16x8 K16 B-frag.
// (R1/R2/R5/R7/R10/R11-verified correct.)
__device__ __forceinline__ f16x8 swap_pack(f16x4 a, f16x4 b) {
    u32x2 au = __builtin_bit_cast(u32x2, a);
    u32x2 bu = __builtin_bit_cast(u32x2, b);
    unsigned a0 = au[0], a1 = au[1], b0 = bu[0], b1 = bu[1];
    asm("v_permlane32_swap_b32 %0, %1" : "+v"(a0), "+v"(b0));
    asm("v_permlane32_swap_b32 %0, %1" : "+v"(a1), "+v"(b1));
    u32x4 r = {a0, a1, b0, b1};
    return __builtin_bit_cast(f16x8, r);
}

// ---------------------------------------------------------------------------
// Kernel P: pack Wall = [Wq*(1/ln2); Wk; Wv] (320x256) to f16 + bias vector.
// grid: 320 blocks, 256 threads.
// ---------------------------------------------------------------------------
__global__ __launch_bounds__(256) void wall_prep(
    const float* __restrict__ Wq, const float* __restrict__ bq,
    const float* __restrict__ Wk, const float* __restrict__ bk,
    const float* __restrict__ Wv, const float* __restrict__ bv,
    f16* __restrict__ Wall, float* __restrict__ bias_all) {
    int r = blockIdx.x;
    int t = threadIdx.x;
    const float SC = 1.4426950408889634f;  // 1/ln2 folded into q rows
    const float* src;
    float scale, bsc;
    if (r < 32)      { src = Wq + (size_t)r * Cx;        scale = SC;  bsc = bq[r] * SC; }
    else if (r < 64) { src = Wk + (size_t)(r - 32) * Cx; scale = 1.f; bsc = bk[r - 32]; }
    else             { src = Wv + (size_t)(r - 64) * Cx; scale = 1.f; bsc = bv[r - 64]; }
    Wall[(size_t)r * Cx + t] = (f16)(src[t] * scale);
    if (t == 0) bias_all[r] = bsc;
}

// ---------------------------------------------------------------------------
// Kernel G: unified projection GEMM on the matrix pipe (replaces qk_proj AND
// v_proj — v_proj was 139 us of VALU-GEMM with a 64-line wrow gather).
// Per block: one 32-row tile of Wall x 256 n-columns (4 waves x 64n).
//  - x staged per k-step into LDS via COLUMN GATHER (thread t owns column
//    n0+t: 16 coalesced-across-lanes loads, 2x ds_write_b128 — no transposed
//    LDS writes). Row length 24 f16 = 48 B: 16B-aligned b128, <=4-way conflict.
//  - one fragment load serves as A or B (identical lane patterns):
//      q/k rows:  mfma(wf, xf) -> D[d][n]  -> [b][n][d] layout stores
//      V rows:    mfma(xf, wf) -> D[n][c]  -> [b][c][n] layout stores
// grid: Bx * 10 * 9 = 1440 blocks, 256 threads.
// ---------------------------------------------------------------------------
#define PG_ROWLEN 24
__global__ __launch_bounds__(256) void proj_gemm(
    const float* __restrict__ x,
    const f16* __restrict__ Wall, const float* __restrict__ bias_all,
    f16* __restrict__ qws, f16* __restrict__ kws, f16* __restrict__ vws) {
    __shared__ __align__(16) f16 xs[256 * PG_ROWLEN];   // 12 KB
    int bid = blockIdx.x;
    int nt = bid % 9;   bid /= 9;
    int rt = bid % 10;  bid /= 10;
    int b  = bid;
    int n0 = nt * 256;
    int r0 = rt * 32;
    int t  = threadIdx.x;
    int wv = t >> 6, il = t & 31, h = (t >> 5) & 1;

    const float* xb = x + (size_t)b * Cx * Nx + n0 + t;         // column gather
    const f16*   wp = Wall + (size_t)(r0 + il) * Cx + h * 8;    // frag row

    f32x16 acc[2];
    acc[0] = (f32x16){};
    acc[1] = (f32x16){};
    int nb = wv * 64 + il;   // frag n-row base (second frag adds 32)

    for (int ks = 0; ks < 16; ++ks) {
        // ---- stage x[k0..k0+15][n0+t] -> xs[t][0..15] (f16) ----
        float xv[16];
#pragma unroll
        for (int kk = 0; kk < 16; ++kk)
            xv[kk] = xb[(size_t)(ks * 16 + kk) * Nx];
        f16x8 p0, p1;
#pragma unroll
        for (int kk = 0; kk < 8; ++kk) {
            p0[kk] = (f16)xv[kk];
            p1[kk] = (f16)xv[8 + kk];
        }
        __syncthreads();             // prior iteration's frag reads done
        *(f16x8*)&xs[t * PG_ROWLEN]     = p0;
        *(f16x8*)&xs[t * PG_ROWLEN + 8] = p1;
        __syncthreads();

        f16x8 wf  = *(const f16x8*)(wp + ks * 16);
        f16x8 xf0 = *(const f16x8*)&xs[nb * PG_ROWLEN + h * 8];
        f16x8 xf1 = *(const f16x8*)&xs[(nb + 32) * PG_ROWLEN + h * 8];
        __builtin_amdgcn_s_setprio(1);
        if (rt < 2) {   // q/k: rows = output dim d
            acc[0] = MFMA_K16(wf, xf0, acc[0]);
            acc[1] = MFMA_K16(wf, xf1, acc[1]);
        } else {        // V: rows = n (transposed output, n-contiguous stores)
            acc[0] = MFMA_K16(xf0, wf, acc[0]);
            acc[1] = MFMA_K16(xf1, wf, acc[1]);
        }
        __builtin_amdgcn_s_setprio(0);
    }

    if (rt < 2) {
        // D[m=d][col=n]: n = n0 + wv*64 + f*32 + il; d = (r&3)+8g+4h
        f16* dst = rt ? kws : qws;
#pragma unroll
        for (int f = 0; f < 2; ++f) {
            int n = n0 + wv * 64 + f * 32 + il;
            size_t base = ((size_t)b * Nx + n) * Dx + 4 * h;
#pragma unroll
            for (int g = 0; g < 4; ++g) {
                f16x4 o;
#pragma unroll
                for (int rr = 0; rr < 4; ++rr)
                    o[rr] = (f16)(acc[f][4 * g + rr] +
                                  bias_all[r0 + 8 * g + 4 * h + rr]);
                *(f16x4*)(dst + base + 8 * g) = o;
            }
        }
    } else {
        // D[m=n][col=c]: c = (rt-2)*32 + il; n = n0 + wv*64 + f*32 + (r&3)+8g+4h
        int c = (rt - 2) * 32 + il;
        float bvv = bias_all[r0 + il];
#pragma unroll
        for (int f = 0; f < 2; ++f) {
            size_t base = ((size_t)b * Cx + c) * Nx + n0 + wv * 64 + f * 32 + 4 * h;
#pragma unroll
            for (int g = 0; g < 4; ++g) {
                f16x4 o;
#pragma unroll
                for (int rr = 0; rr < 4; ++rr)
                    o[rr] = (f16)(acc[f][4 * g + rr] + bvv);
                *(f16x4*)(vws + base + 8 * g) = o;
            }
        }
    }
}

// ---------------------------------------------------------------------------
// Kernel C: softmax column sums  s[b][j] = sum_i exp2(E[i,j]).
// (R11-passing, unchanged.)
// ---------------------------------------------------------------------------
__global__ __launch_bounds__(256, 4) void col_stats(
    const f16* __restrict__ qhi, const f16* __restrict__ khi,
    float* __restrict__ s) {
    __shared__ float part[4][32];
    int jt = blockIdx.x % 72;
    int b  = blockIdx.x / 72;
    int j0 = jt * 32;
    int t  = threadIdx.x;
    int w  = t >> 6;              // wave id 0..3
    int il = t & 31, h = (t >> 5) & 1;

    f16x8 kh[2];
#pragma unroll
    for (int ks = 0; ks < 2; ++ks)
        kh[ks] = *(const f16x8*)(khi + ((size_t)b * Nx + j0 + il) * Dx + h * 8 + ks * 16);

    f32x16 sacc = {};
    for (int it = w * 18; it < w * 18 + 18; ++it) {
        f16x8 qh[2];
#pragma unroll
        for (int ks = 0; ks < 2; ++ks)
            qh[ks] = *(const f16x8*)(qhi + ((size_t)b * Nx + it * 32 + il) * Dx + h * 8 + ks * 16);
        f32x16 e = {};
        __builtin_amdgcn_s_setprio(1);
        e = MFMA_K16(kh[0], qh[0], e);
        e = MFMA_K16(kh[1], qh[1], e);
        __builtin_amdgcn_s_setprio(0);
#pragma unroll
        for (int r = 0; r < 16; ++r) sacc[r] += EXP2F(e[r]);
    }
#pragma unroll
    for (int r = 0; r < 16; ++r) {
        float v = sacc[r];
        for (int msk = 1; msk <= 16; msk <<= 1) v += __shfl_xor(v, msk);
        if (il == 0) part[w][(r & 3) + 8 * (r >> 2) + 4 * h] = v;
    }
    __syncthreads();
    if (t < 32)
        s[(size_t)b * Nx + j0 + t] =
            part[0][t] + part[1][t] + part[2][t] + part[3][t];
}

// ---------------------------------------------------------------------------
// Kernel D: main attention. (R11-passing, unchanged.)
// grid: Bx * 36 * 4 = 2304 blocks, 128 threads (2 waves = j-halves).
// ---------------------------------------------------------------------------
__global__ __launch_bounds__(128, 3) void attn_out(
    const f16* __restrict__ qhi, const f16* __restrict__ khi,
    const f16* __restrict__ vhi,
    const float* __restrict__ s, const float* __restrict__ x,
    const float* __restrict__ gamma, float* __restrict__ out) {
    __shared__ __align__(16) float rs[Nx];     // 9216 B
    __shared__ float red[64][33];              // 8448 B, padded, chunk-reused
    int blk = blockIdx.x;
    int w4   = blk & 3;  blk >>= 2;     // c-quarter
    int it64 = blk % 36;
    int b    = blk / 36;
    int i0   = it64 * 64;
    int c0   = w4 * 64;
    int t = threadIdx.x;
    int jh   = t >> 6;                  // wave id = j-half (0..1)
    int lane = t & 63;
    int il = t & 31, h = (t >> 5) & 1;

    {   // stage reciprocal sums (128 threads)
        const f32x4* s4 = (const f32x4*)(s + (size_t)b * Nx);
        f32x4* rs4 = (f32x4*)rs;
        for (int r = t; r < Nx / 4; r += 128) {
            f32x4 v = s4[r];
            rs4[r] = (f32x4){1.0f / v[0], 1.0f / v[1], 1.0f / v[2], 1.0f / v[3]};
        }
    }
    __syncthreads();

    // Q as B-operand for E^T, both i-subtiles, hoisted
    f16x8 qh[2][2];   // [itile][ks]
#pragma unroll
    for (int itile = 0; itile < 2; ++itile)
#pragma unroll
        for (int ks = 0; ks < 2; ++ks)
            qh[itile][ks] = *(const f16x8*)(qhi +
                ((size_t)b * Nx + i0 + itile * 32 + il) * Dx + h * 8 + ks * 16);

    f32x16 acc[2][2];  // [itile][cg]
#pragma unroll
    for (int a = 0; a < 2; ++a)
#pragma unroll
        for (int cgi = 0; cgi < 2; ++cgi) acc[a][cgi] = (f32x16){};

    int jb = jh * 36 * 32;
    const f16* kph = khi + ((size_t)b * Nx + jb + il) * Dx + h * 8;
    const f16* vph = vhi + ((size_t)b * Cx + c0 + il) * Nx + jb + h * 8;

    // K and V register double-buffers, both at prefetch distance 2
    f16x8 kb[2][2];     // [buf][ks]
    f16x8 vb[2][2][2];  // [buf][cg][gp]

#pragma unroll
    for (int ks = 0; ks < 2; ++ks) {
        kb[0][ks] = *(const f16x8*)(kph + ks * 16);
        kb[1][ks] = *(const f16x8*)(kph + 1024 + ks * 16);
    }
#pragma unroll
    for (int cg = 0; cg < 2; ++cg)
#pragma unroll
        for (int gp = 0; gp < 2; ++gp) {
            size_t voff = (size_t)cg * 32 * Nx + gp * 16;
            vb[0][cg][gp] = *(const f16x8*)(vph + voff);
            vb[1][cg][gp] = *(const f16x8*)(vph + voff + 32);
        }

#pragma unroll 2
    for (int jt = 0; jt < 36; ++jt) {
        int cur = jt & 1;
        int j0  = jb + jt * 32;
#pragma unroll
        for (int itile = 0; itile < 2; ++itile) {
            f32x16 e = {};
            __builtin_amdgcn_s_setprio(1);
            e = MFMA_K16(kb[cur][0], qh[itile][0], e);
            e = MFMA_K16(kb[cur][1], qh[itile][1], e);
            __builtin_amdgcn_s_setprio(0);
            f16x4 ph4[4];
#pragma unroll
            for (int g = 0; g < 4; ++g) {
                f32x4 rsv = *(const f32x4*)&rs[j0 + 8 * g + 4 * h];
#pragma unroll
                for (int jj = 0; jj < 4; ++jj)
                    ph4[g][jj] = (f16)(EXP2F(e[4 * g + jj]) * rsv[jj]);
            }
            f16x8 phK[2];
            phK[0] = swap_pack(ph4[0], ph4[1]);
            phK[1] = swap_pack(ph4[2], ph4[3]);
            __builtin_amdgcn_s_setprio(1);
#pragma unroll
            for (int cg = 0; cg < 2; ++cg)
#pragma unroll
                for (int gp = 0; gp < 2; ++gp)
                    acc[itile][cg] = MFMA_K16(vb[cur][cg][gp], phK[gp], acc[itile][cg]);
            __builtin_amdgcn_s_setprio(0);
        }
        int kn = (jt + 2 < 36) ? (jt + 2) * 1024 : 0;
#pragma unroll
        for (int ks = 0; ks < 2; ++ks)
            kb[cur][ks] = *(const f16x8*)(kph + kn + ks * 16);
        int vn = (jt + 2 < 36) ? (jt + 2) * 32 : 0;
#pragma unroll
        for (int cg = 0; cg < 2; ++cg)
#pragma unroll
            for (int gp = 0; gp < 2; ++gp) {
                size_t voff = (size_t)cg * 32 * Nx + vn + gp * 16;
                vb[cur][cg][gp] = *(const f16x8*)(vph + voff);
            }
    }

    // ---- combine j-halves via the chunked red buffer (R10-verified) ----
    float gm = gamma[0];
#pragma unroll
    for (int itile = 0; itile < 2; ++itile) {
        __syncthreads();
        if (jh == 1) {
#pragma unroll
            for (int cg = 0; cg < 2; ++cg)
#pragma unroll
                for (int r = 0; r < 16; ++r)
                    red[lane][cg * 16 + r] = acc[itile][cg][r];
        }
        __syncthreads();
        if (jh == 0) {
#pragma unroll
            for (int cg = 0; cg < 2; ++cg)
#pragma unroll
                for (int r = 0; r < 16; ++r) {
                    int c = c0 + cg * 32 + (r & 3) + 8 * (r >> 2) + 4 * h;
                    int i = i0 + itile * 32 + il;
                    size_t idx = ((size_t)b * Cx + c) * Nx + i;
                    out[idx] = x[idx] +
                        gm * (acc[itile][cg][r] + red[lane][cg * 16 + r]);
                }
        }
    }
}

// ---------------------------------------------------------------------------
extern "C" void kernel_launch(void* const* d_in, const int* in_sizes, int n_in,
                              void* d_out, int out_size, void* d_ws, size_t ws_size,
                              hipStream_t stream) {
    const float* x     = (const float*)d_in[0];
    const float* Wq    = (const float*)d_in[1];
    const float* bq    = (const float*)d_in[2];
    const float* Wk    = (const float*)d_in[3];
    const float* bk    = (const float*)d_in[4];
    const float* Wv    = (const float*)d_in[5];
    const float* bv    = (const float*)d_in[6];
    const float* gamma = (const float*)d_in[7];
    float* out = (float*)d_out;

    // ws: q,k [b][n][d] f16; V [b][c][n] f16; s [b][n] f32; Wall; bias (~24 MB)
    const size_t QK = (size_t)Bx * Nx * Dx;
    const size_t VN = (size_t)Bx * Cx * Nx;
    f16* qws = (f16*)d_ws;
    f16* kws = qws + QK;
    f16* vws = kws + QK;
    float* s = (float*)(vws + VN);
    f16* Wall = (f16*)(s + (size_t)Bx * Nx);
    float* bias_all = (float*)(Wall + 320 * Cx);

    wall_prep<<<320,            256, 0, stream>>>(Wq, bq, Wk, bk, Wv, bv, Wall, bias_all);
    proj_gemm<<<Bx * 10 * 9,    256, 0, stream>>>(x, Wall, bias_all, qws, kws, vws);
    col_stats<<<Bx * 72,        256, 0, stream>>>(qws, kws, s);
    attn_out <<<Bx * 36 * 4,    128, 0, stream>>>(qws, kws, vws, s, x, gamma, out);
}

// Round 14
// 259.551 us; speedup vs baseline: 2.1299x; 1.0745x over previous
//
#include <hip/hip_runtime.h>

// Shapes (fixed by the problem)
#define Bx 16
#define Cx 256
#define Dx 32
#define Nx 2304   // 48*48

typedef _Float16 f16;
typedef _Float16 f16x4 __attribute__((ext_vector_type(4)));
typedef _Float16 f16x8 __attribute__((ext_vector_type(8)));
typedef float    f32x4 __attribute__((ext_vector_type(4)));
typedef float    f32x16 __attribute__((ext_vector_type(16)));
typedef unsigned int u32x2 __attribute__((ext_vector_type(2)));
typedef unsigned int u32x4 __attribute__((ext_vector_type(4)));

// A,B fragment layouts (gfx950):
//  A: lane holds A[m=lane%32][k=(lane/32)*8 + 0..7]  (f16x8)
//  B: lane holds B[k=(lane/32)*8 + 0..7][n=lane%32]  — same per-lane pattern.
//  C/D: col=lane&31, row=(reg&3)+8*(reg>>2)+4*(lane>>5)  [verified]
#define MFMA_K16(a, b, c) __builtin_amdgcn_mfma_f32_32x32x16_f16((a), (b), (c), 0, 0, 0)
#define EXP2F(x) __builtin_amdgcn_exp2f(x)
// cvt_pkrtz returns __fp16-vec; bit_cast to dword immediately (same size).
#define PKRTZ_U32(lo, hi) __builtin_bit_cast(unsigned, __builtin_amdgcn_cvt_pkrtz((lo), (hi)))

// Repack K8-layout P dwords into one f16x8 K16 B-frag via cross-half permlane
// swap. (R12-verified path, now fed directly by cvt_pkrtz dwords.)
__device__ __forceinline__ f16x8 swap_pack4(unsigned a0, unsigned a1,
                                            unsigned b0, unsigned b1) {
    asm("v_permlane32_swap_b32 %0, %1" : "+v"(a0), "+v"(b0));
    asm("v_permlane32_swap_b32 %0, %1" : "+v"(a1), "+v"(b1));
    u32x4 r = {a0, a1, b0, b1};
    return __builtin_bit_cast(f16x8, r);
}

// XCD-aware logical block id (T1): HW round-robins blockIdx%8 across XCDs;
// this mapping gives each XCD a CONTIGUOUS logical range so all blocks of a
// batch b (b is the slowest-decoded field everywhere) share one XCD's L2.
__device__ __forceinline__ int xcd_swz(int nwg8) {
    int bid = blockIdx.x;
    return (bid & 7) * nwg8 + (bid >> 3);
}

// ---------------------------------------------------------------------------
// Kernel P: pack Wall = [Wq*(1/ln2); Wk; Wv] (320x256) to f16 + bias vector.
// ---------------------------------------------------------------------------
__global__ __launch_bounds__(256) void wall_prep(
    const float* __restrict__ Wq, const float* __restrict__ bq,
    const float* __restrict__ Wk, const float* __restrict__ bk,
    const float* __restrict__ Wv, const float* __restrict__ bv,
    f16* __restrict__ Wall, float* __restrict__ bias_all) {
    int r = blockIdx.x;
    int t = threadIdx.x;
    const float SC = 1.4426950408889634f;  // 1/ln2 folded into q rows
    const float* src;
    float scale, bsc;
    if (r < 32)      { src = Wq + (size_t)r * Cx;        scale = SC;  bsc = bq[r] * SC; }
    else if (r < 64) { src = Wk + (size_t)(r - 32) * Cx; scale = 1.f; bsc = bk[r - 32]; }
    else             { src = Wv + (size_t)(r - 64) * Cx; scale = 1.f; bsc = bv[r - 64]; }
    Wall[(size_t)r * Cx + t] = (f16)(src[t] * scale);
    if (t == 0) bias_all[r] = bsc;
}

// ---------------------------------------------------------------------------
// Kernel G: unified projection GEMM (R12-passing; + XCD swizzle: 90 blocks of
// each b land on one XCD, so the 10x re-read of x[b] (2.4 MB) is L2-served).
// grid: Bx * 10 * 9 = 1440 blocks, 256 threads.
// ---------------------------------------------------------------------------
#define PG_ROWLEN 24
__global__ __launch_bounds__(256) void proj_gemm(
    const float* __restrict__ x,
    const f16* __restrict__ Wall, const float* __restrict__ bias_all,
    f16* __restrict__ qws, f16* __restrict__ kws, f16* __restrict__ vws) {
    __shared__ __align__(16) f16 xs[256 * PG_ROWLEN];   // 12 KB
    int bid = xcd_swz(180);            // 1440/8
    int nt = bid % 9;   bid /= 9;
    int rt = bid % 10;  bid /= 10;
    int b  = bid;
    int n0 = nt * 256;
    int r0 = rt * 32;
    int t  = threadIdx.x;
    int wv = t >> 6, il = t & 31, h = (t >> 5) & 1;

    const float* xb = x + (size_t)b * Cx * Nx + n0 + t;         // column gather
    const f16*   wp = Wall + (size_t)(r0 + il) * Cx + h * 8;    // frag row

    f32x16 acc[2];
    acc[0] = (f32x16){};
    acc[1] = (f32x16){};
    int nb = wv * 64 + il;   // frag n-row base (second frag adds 32)

    for (int ks = 0; ks < 16; ++ks) {
        float xv[16];
#pragma unroll
        for (int kk = 0; kk < 16; ++kk)
            xv[kk] = xb[(size_t)(ks * 16 + kk) * Nx];
        f16x8 p0, p1;
#pragma unroll
        for (int kk = 0; kk < 8; ++kk) {
            p0[kk] = (f16)xv[kk];
            p1[kk] = (f16)xv[8 + kk];
        }
        __syncthreads();
        *(f16x8*)&xs[t * PG_ROWLEN]     = p0;
        *(f16x8*)&xs[t * PG_ROWLEN + 8] = p1;
        __syncthreads();

        f16x8 wf  = *(const f16x8*)(wp + ks * 16);
        f16x8 xf0 = *(const f16x8*)&xs[nb * PG_ROWLEN + h * 8];
        f16x8 xf1 = *(const f16x8*)&xs[(nb + 32) * PG_ROWLEN + h * 8];
        __builtin_amdgcn_s_setprio(1);
        if (rt < 2) {
            acc[0] = MFMA_K16(wf, xf0, acc[0]);
            acc[1] = MFMA_K16(wf, xf1, acc[1]);
        } else {
            acc[0] = MFMA_K16(xf0, wf, acc[0]);
            acc[1] = MFMA_K16(xf1, wf, acc[1]);
        }
        __builtin_amdgcn_s_setprio(0);
    }

    if (rt < 2) {
        f16* dst = rt ? kws : qws;
#pragma unroll
        for (int f = 0; f < 2; ++f) {
            int n = n0 + wv * 64 + f * 32 + il;
            size_t base = ((size_t)b * Nx + n) * Dx + 4 * h;
#pragma unroll
            for (int g = 0; g < 4; ++g) {
                f16x4 o;
#pragma unroll
                for (int rr = 0; rr < 4; ++rr)
                    o[rr] = (f16)(acc[f][4 * g + rr] +
                                  bias_all[r0 + 8 * g + 4 * h + rr]);
                *(f16x4*)(dst + base + 8 * g) = o;
            }
        }
    } else {
        int c = (rt - 2) * 32 + il;
        float bvv = bias_all[r0 + il];
#pragma unroll
        for (int f = 0; f < 2; ++f) {
            size_t base = ((size_t)b * Cx + c) * Nx + n0 + wv * 64 + f * 32 + 4 * h;
#pragma unroll
            for (int g = 0; g < 4; ++g) {
                f16x4 o;
#pragma unroll
                for (int rr = 0; rr < 4; ++rr)
                    o[rr] = (f16)(acc[f][4 * g + rr] + bvv);
                *(f16x4*)(vws + base + 8 * g) = o;
            }
        }
    }
}

// ---------------------------------------------------------------------------
// Kernel C: softmax column sums  s[b][j] = sum_i exp2(E[i,j]).
// (R11/R12-passing; + XCD swizzle: 72 blocks of each b share one L2, so the
// 72x re-read of Q[b] (147 KB) is L2-served.)
// grid: Bx * 72 blocks, 256 threads.
// ---------------------------------------------------------------------------
__global__ __launch_bounds__(256, 4) void col_stats(
    const f16* __restrict__ qhi, const f16* __restrict__ khi,
    float* __restrict__ s) {
    __shared__ float part[4][32];
    int blk = xcd_swz(144);            // 1152/8
    int jt = blk % 72;
    int b  = blk / 72;
    int j0 = jt * 32;
    int t  = threadIdx.x;
    int w  = t >> 6;
    int il = t & 31, h = (t >> 5) & 1;

    f16x8 kh[2];
#pragma unroll
    for (int ks = 0; ks < 2; ++ks)
        kh[ks] = *(const f16x8*)(khi + ((size_t)b * Nx + j0 + il) * Dx + h * 8 + ks * 16);

    f32x16 sacc = {};
    for (int it = w * 18; it < w * 18 + 18; ++it) {
        f16x8 qh[2];
#pragma unroll
        for (int ks = 0; ks < 2; ++ks)
            qh[ks] = *(const f16x8*)(qhi + ((size_t)b * Nx + it * 32 + il) * Dx + h * 8 + ks * 16);
        f32x16 e = {};
        __builtin_amdgcn_s_setprio(1);
        e = MFMA_K16(kh[0], qh[0], e);
        e = MFMA_K16(kh[1], qh[1], e);
        __builtin_amdgcn_s_setprio(0);
#pragma unroll
        for (int r = 0; r < 16; ++r) sacc[r] += EXP2F(e[r]);
    }
#pragma unroll
    for (int r = 0; r < 16; ++r) {
        float v = sacc[r];
        for (int msk = 1; msk <= 16; msk <<= 1) v += __shfl_xor(v, msk);
        if (il == 0) part[w][(r & 3) + 8 * (r >> 2) + 4 * h] = v;
    }
    __syncthreads();
    if (t < 32)
        s[(size_t)b * Nx + j0 + t] =
            part[0][t] + part[1][t] + part[2][t] + part[3][t];
}

// ---------------------------------------------------------------------------
// Kernel D: main attention.  R14 = R13 with the compile fix (PKRTZ_U32).
//  - rs[] holds lrs = -log2(s); the E-MFMA C-operand is initialized with
//    lrs[j] (C row IS j), so P = exp2(E) directly — deletes 32 v_mul/iter and
//    halves the per-iter LDS reads.
//  - packed f16 conversion via cvt_pkrtz feeds swap_pack4 dwords directly.
//  - XCD swizzle: 144 blocks of each b share one XCD L2 (Q+K+V[b] = 2.7 MB).
// grid: Bx * 36 * 4 = 2304 blocks, 128 threads (2 waves = j-halves).
// ---------------------------------------------------------------------------
__global__ __launch_bounds__(128, 3) void attn_out(
    const f16* __restrict__ qhi, const f16* __restrict__ khi,
    const f16* __restrict__ vhi,
    const float* __restrict__ s, const float* __restrict__ x,
    const float* __restrict__ gamma, float* __restrict__ out) {
    __shared__ __align__(16) float rs[Nx];     // 9216 B: -log2(s)
    __shared__ float red[64][33];              // 8448 B, padded, chunk-reused
    int blk = xcd_swz(288);            // 2304/8
    int w4   = blk & 3;  blk >>= 2;
    int it64 = blk % 36;
    int b    = blk / 36;
    int i0   = it64 * 64;
    int c0   = w4 * 64;
    int t = threadIdx.x;
    int jh   = t >> 6;
    int lane = t & 63;
    int il = t & 31, h = (t >> 5) & 1;

    {   // stage -log2(sum) (128 threads)
        const f32x4* s4 = (const f32x4*)(s + (size_t)b * Nx);
        f32x4* rs4 = (f32x4*)rs;
        for (int r = t; r < Nx / 4; r += 128) {
            f32x4 v = s4[r];
            rs4[r] = (f32x4){-__log2f(v[0]), -__log2f(v[1]),
                             -__log2f(v[2]), -__log2f(v[3])};
        }
    }
    __syncthreads();

    // Q as B-operand for E^T, both i-subtiles, hoisted
    f16x8 qh[2][2];   // [itile][ks]
#pragma unroll
    for (int itile = 0; itile < 2; ++itile)
#pragma unroll
        for (int ks = 0; ks < 2; ++ks)
            qh[itile][ks] = *(const f16x8*)(qhi +
                ((size_t)b * Nx + i0 + itile * 32 + il) * Dx + h * 8 + ks * 16);

    f32x16 acc[2][2];  // [itile][cg]
#pragma unroll
    for (int a = 0; a < 2; ++a)
#pragma unroll
        for (int cgi = 0; cgi < 2; ++cgi) acc[a][cgi] = (f32x16){};

    int jb = jh * 36 * 32;
    const f16* kph = khi + ((size_t)b * Nx + jb + il) * Dx + h * 8;
    const f16* vph = vhi + ((size_t)b * Cx + c0 + il) * Nx + jb + h * 8;

    // K and V register double-buffers, both at prefetch distance 2
    f16x8 kb[2][2];     // [buf][ks]
    f16x8 vb[2][2][2];  // [buf][cg][gp]

#pragma unroll
    for (int ks = 0; ks < 2; ++ks) {
        kb[0][ks] = *(const f16x8*)(kph + ks * 16);
        kb[1][ks] = *(const f16x8*)(kph + 1024 + ks * 16);
    }
#pragma unroll
    for (int cg = 0; cg < 2; ++cg)
#pragma unroll
        for (int gp = 0; gp < 2; ++gp) {
            size_t voff = (size_t)cg * 32 * Nx + gp * 16;
            vb[0][cg][gp] = *(const f16x8*)(vph + voff);
            vb[1][cg][gp] = *(const f16x8*)(vph + voff + 32);
        }

#pragma unroll 2
    for (int jt = 0; jt < 36; ++jt) {
        int cur = jt & 1;
        int j0  = jb + jt * 32;
        // ---- E C-init: ev[4g+jj] = lrs[j0 + jj + 8g + 4h] (shared itiles) --
        f32x16 ev;
#pragma unroll
        for (int g = 0; g < 4; ++g) {
            f32x4 rv = *(const f32x4*)&rs[j0 + 8 * g + 4 * h];
#pragma unroll
            for (int jj = 0; jj < 4; ++jj) ev[4 * g + jj] = rv[jj];
        }
#pragma unroll
        for (int itile = 0; itile < 2; ++itile) {
            // ---- E^T tile with folded -log2(s) (2 MFMA) ----
            f32x16 e;
            __builtin_amdgcn_s_setprio(1);
            e = MFMA_K16(kb[cur][0], qh[itile][0], ev);
            e = MFMA_K16(kb[cur][1], qh[itile][1], e);
            __builtin_amdgcn_s_setprio(0);
            // ---- P = exp2(E), packed f16 -> K16 frags ----
            unsigned pk[4][2];
#pragma unroll
            for (int g = 0; g < 4; ++g) {
                pk[g][0] = PKRTZ_U32(EXP2F(e[4 * g]),     EXP2F(e[4 * g + 1]));
                pk[g][1] = PKRTZ_U32(EXP2F(e[4 * g + 2]), EXP2F(e[4 * g + 3]));
            }
            f16x8 phK[2];
            phK[0] = swap_pack4(pk[0][0], pk[0][1], pk[1][0], pk[1][1]);
            phK[1] = swap_pack4(pk[2][0], pk[2][1], pk[3][0], pk[3][1]);
            // ---- PV (4 MFMA) ----
            __builtin_amdgcn_s_setprio(1);
#pragma unroll
            for (int cg = 0; cg < 2; ++cg)
#pragma unroll
                for (int gp = 0; gp < 2; ++gp)
                    acc[itile][cg] = MFMA_K16(vb[cur][cg][gp], phK[gp], acc[itile][cg]);
            __builtin_amdgcn_s_setprio(0);
        }
        // ---- issue K(jt+2), V(jt+2) into buf cur ----
        int kn = (jt + 2 < 36) ? (jt + 2) * 1024 : 0;
#pragma unroll
        for (int ks = 0; ks < 2; ++ks)
            kb[cur][ks] = *(const f16x8*)(kph + kn + ks * 16);
        int vn = (jt + 2 < 36) ? (jt + 2) * 32 : 0;
#pragma unroll
        for (int cg = 0; cg < 2; ++cg)
#pragma unroll
            for (int gp = 0; gp < 2; ++gp) {
                size_t voff = (size_t)cg * 32 * Nx + vn + gp * 16;
                vb[cur][cg][gp] = *(const f16x8*)(vph + voff);
            }
    }

    // ---- combine j-halves via the chunked red buffer (R10-verified) ----
    float gm = gamma[0];
#pragma unroll
    for (int itile = 0; itile < 2; ++itile) {
        __syncthreads();
        if (jh == 1) {
#pragma unroll
            for (int cg = 0; cg < 2; ++cg)
#pragma unroll
                for (int r = 0; r < 16; ++r)
                    red[lane][cg * 16 + r] = acc[itile][cg][r];
        }
        __syncthreads();
        if (jh == 0) {
#pragma unroll
            for (int cg = 0; cg < 2; ++cg)
#pragma unroll
                for (int r = 0; r < 16; ++r) {
                    int c = c0 + cg * 32 + (r & 3) + 8 * (r >> 2) + 4 * h;
                    int i = i0 + itile * 32 + il;
                    size_t idx = ((size_t)b * Cx + c) * Nx + i;
                    out[idx] = x[idx] +
                        gm * (acc[itile][cg][r] + red[lane][cg * 16 + r]);
                }
        }
    }
}

// ---------------------------------------------------------------------------
extern "C" void kernel_launch(void* const* d_in, const int* in_sizes, int n_in,
                              void* d_out, int out_size, void* d_ws, size_t ws_size,
                              hipStream_t stream) {
    const float* x     = (const float*)d_in[0];
    const float* Wq    = (const float*)d_in[1];
    const float* bq    = (const float*)d_in[2];
    const float* Wk    = (const float*)d_in[3];
    const float* bk    = (const float*)d_in[4];
    const float* Wv    = (const float*)d_in[5];
    const float* bv    = (const float*)d_in[6];
    const float* gamma = (const float*)d_in[7];
    float* out = (float*)d_out;

    // ws: q,k [b][n][d] f16; V [b][c][n] f16; s [b][n] f32; Wall; bias (~24 MB)
    const size_t QK = (size_t)Bx * Nx * Dx;
    const size_t VN = (size_t)Bx * Cx * Nx;
    f16* qws = (f16*)d_ws;
    f16* kws = qws + QK;
    f16* vws = kws + QK;
    float* s = (float*)(vws + VN);
    f16* Wall = (f16*)(s + (size_t)Bx * Nx);
    float* bias_all = (float*)(Wall + 320 * Cx);

    wall_prep<<<320,            256, 0, stream>>>(Wq, bq, Wk, bk, Wv, bv, Wall, bias_all);
    proj_gemm<<<Bx * 10 * 9,    256, 0, stream>>>(x, Wall, bias_all, qws, kws, vws);
    col_stats<<<Bx * 72,        256, 0, stream>>>(qws, kws, s);
    attn_out <<<Bx * 36 * 4,    128, 0, stream>>>(qws, kws, vws, s, x, gamma, out);
}